// Round 4
// baseline (247.675 us; speedup 1.0000x reference)
//
#include <hip/hip_runtime.h>

#define M_DIM 4096
#define N_DIM 4096
#define K_DIM 4096

typedef __attribute__((ext_vector_type(4))) int i32x4;
typedef __attribute__((ext_vector_type(16))) int i32x16;

typedef __attribute__((address_space(1))) const void GV;
typedef __attribute__((address_space(3))) void LV;

// ---------------------------------------------------------------------------
// Fused pre-kernel (unchanged).
//  blocks [0,1024):    hadamard (FWHT over 64 groups) + per-token absmax
//                      int8 quant; writes xq (i8) + sx (f32/token).
//  blocks [1024,2048): weight int8 recovery: per-row scale = absmax/127;
//                      writes wq (i8) + sw (f32/row).
// ---------------------------------------------------------------------------
__global__ __launch_bounds__(256) void prequant_kernel(const float* __restrict__ x,
                                                       const float* __restrict__ w,
                                                       char* __restrict__ xq,
                                                       char* __restrict__ wq,
                                                       float* __restrict__ sx,
                                                       float* __restrict__ sw) {
  const int wave = threadIdx.x >> 6;
  const int lane = threadIdx.x & 63;

  if (blockIdx.x >= 1024) {
    const int row = (blockIdx.x - 1024) * 4 + wave;
    const float* wp = w + (size_t)row * 4096;
    float4 v[16];
#pragma unroll
    for (int c = 0; c < 16; ++c) v[c] = *(const float4*)(wp + c * 256 + lane * 4);
    float amax = 0.f;
#pragma unroll
    for (int c = 0; c < 16; ++c)
      amax = fmaxf(amax, fmaxf(fmaxf(fabsf(v[c].x), fabsf(v[c].y)),
                               fmaxf(fabsf(v[c].z), fabsf(v[c].w))));
#pragma unroll
    for (int off = 32; off >= 1; off >>= 1) amax = fmaxf(amax, __shfl_xor(amax, off, 64));
    amax = fmaxf(amax, 1e-30f);
    const float inv = 127.0f / amax;
    char* op = wq + (size_t)row * 4096;
#pragma unroll
    for (int c = 0; c < 16; ++c) {
      char4 o;
      o.x = (char)rintf(v[c].x * inv);
      o.y = (char)rintf(v[c].y * inv);
      o.z = (char)rintf(v[c].z * inv);
      o.w = (char)rintf(v[c].w * inv);
      *(char4*)(op + c * 256 + lane * 4) = o;
    }
    if (lane == 0) sw[row] = amax * (1.0f / 127.0f);
    return;
  }

  const int tok = blockIdx.x * 4 + wave;
  const int gs = lane >> 4;
  const int q = lane & 15;
  const float* xp = x + (size_t)tok * 4096;

  float4 v[16];
#pragma unroll
  for (int gl = 0; gl < 16; ++gl)
    v[gl] = *(const float4*)(xp + (gl * 4 + gs) * 64 + q * 4);

#pragma unroll
  for (int s = 1; s < 16; s <<= 1) {
#pragma unroll
    for (int i = 0; i < 16; ++i) {
      if ((i & s) == 0) {
        float4 a = v[i], b = v[i | s];
        v[i].x = a.x + b.x; v[i].y = a.y + b.y; v[i].z = a.z + b.z; v[i].w = a.w + b.w;
        v[i | s].x = a.x - b.x; v[i | s].y = a.y - b.y;
        v[i | s].z = a.z - b.z; v[i | s].w = a.w - b.w;
      }
    }
  }
#pragma unroll
  for (int st = 0; st < 2; ++st) {
    const int L = 16 << st;
    const bool hi = (lane & L) != 0;
#pragma unroll
    for (int i = 0; i < 16; ++i) {
      float4 t;
      t.x = __shfl_xor(v[i].x, L, 64);
      t.y = __shfl_xor(v[i].y, L, 64);
      t.z = __shfl_xor(v[i].z, L, 64);
      t.w = __shfl_xor(v[i].w, L, 64);
      if (hi) {
        v[i].x = t.x - v[i].x; v[i].y = t.y - v[i].y;
        v[i].z = t.z - v[i].z; v[i].w = t.w - v[i].w;
      } else {
        v[i].x += t.x; v[i].y += t.y; v[i].z += t.z; v[i].w += t.w;
      }
    }
  }

  float amax = 0.f;
#pragma unroll
  for (int i = 0; i < 16; ++i) {
    v[i].x *= 0.125f; v[i].y *= 0.125f; v[i].z *= 0.125f; v[i].w *= 0.125f;
    amax = fmaxf(amax, fmaxf(fmaxf(fabsf(v[i].x), fabsf(v[i].y)),
                             fmaxf(fabsf(v[i].z), fabsf(v[i].w))));
  }
#pragma unroll
  for (int off = 32; off >= 1; off >>= 1) amax = fmaxf(amax, __shfl_xor(amax, off, 64));

  const float s = fmaxf(amax * (1.0f / 127.0f), 1e-5f);
  const float inv = 1.0f / s;

  char* op = xq + (size_t)tok * 4096;
#pragma unroll
  for (int gl = 0; gl < 16; ++gl) {
    char4 o;
    o.x = (char)rintf(v[gl].x * inv);
    o.y = (char)rintf(v[gl].y * inv);
    o.z = (char)rintf(v[gl].z * inv);
    o.w = (char)rintf(v[gl].w * inv);
    *(char4*)(op + (gl * 4 + gs) * 64 + q * 4) = o;
  }
  if (lane == 0) sx[tok] = s;
}

// ---------------------------------------------------------------------------
// Int8 GEMM: AITER-shaped K-loop (one barrier + one counted vmcnt per K-tile,
// every fragment read exactly once) x 2 BLOCKS PER CU for cross-block
// MFMA/LDS overlap (m114): while one block sits at its barrier/vmcnt, the
// other block's waves feed the MFMA pipe.
//
// Tile 256x128, 256 thr = 4 waves (2M x 2N), per-wave 128x64 = 4x2 frags of
// mfma_i32_32x32x32_i8 (same minimal 0.75 ds_read/MFMA as r3). BK=64 i8
// (64-byte K-rows). LDS: 3-buffer ring x 24KB (A 16KB | B 8KB) = 72KB ->
// exactly 2 blocks/CU; __launch_bounds__(256,2) pins 2 waves/SIMD.
//
// Per K-tile per wave: 12 ds_read_b128 -> 16 MFMA, stage tile t+2 (6 x
// global_load_lds 16B per thread) into t-1's buffer, gate end-of-tile at
// COUNTED vmcnt(6) (t+1 landed, t+2 in flight; never drained until tail),
// one s_barrier. Issue->gate distance = one full tile (>900-cyc HBM lat).
//
// Swizzle (64B rows, both sides): 16B seg s of row r at slot s^((r>>1)&3).
// Stage dest is linear (tid*16 + c*4096: row=(tid>>2)+c*64, slot=tid&3);
// global seg pre-swizzled (tid&3)^((tid>>3)&3) (c*64 rows == 0 mod 4 so the
// involution is c-invariant). Frag reads: row mod 8 == m32 mod 8 for all
// frags -> slot = (kc*2+half)^((m32>>1)&3).
//
// Grid 512 = 2/CU; bijective XCD swizzle over the 16(bm) x 32(bn) grid:
// XCD c gets bm in [(c&3)*4,+4), bn in [(c>>2)*16,+16) -> per-XCD K-slice
// working set A 64KB + B 128KB, L2-resident.
// ---------------------------------------------------------------------------
__global__ __launch_bounds__(256, 2) void gemm_i8(const char* __restrict__ A,
                                                  const char* __restrict__ B,
                                                  const float* __restrict__ sx,
                                                  const float* __restrict__ sw,
                                                  const float* __restrict__ bias,
                                                  float* __restrict__ C) {
  __shared__ __align__(16) char sm[73728];  // 3 x (A 16KB | B 8KB)

  const int tid = threadIdx.x;
  const int lane = tid & 63;
  const int wave = tid >> 6;
  const int wm = wave >> 1;   // 0..1  (M half: 128 rows)
  const int wn = wave & 1;    // 0..1  (N half: 64 cols)
  const int m32 = lane & 31;
  const int half = lane >> 5;

  // XCD-aware bijective swizzle over the 16x32 block grid.
  const int bid = blockIdx.x;
  const int cx = bid & 7, idx = bid >> 3;          // idx 0..63
  const int bm = (cx & 3) * 4 + (idx >> 4);        // 0..15
  const int bn = (cx >> 2) * 16 + (idx & 15);      // 0..31

  // ---- staging: linear LDS dest tid*16 + c*4096 (row=(tid>>2)+c*64,
  //      slot=tid&3); global segment pre-swizzled with the read involution.
  const int strow = tid >> 2;  // 0..63
  const int sseg = ((tid & 3) ^ ((tid >> 3) & 3)) << 4;
  const char* gA0 = A + (size_t)(bm * 256 + strow) * K_DIM + sseg;
  const char* gB0 = B + (size_t)(bn * 128 + strow) * K_DIM + sseg;

#define STAGE(BUFOFF, KO)                                                                \
  {                                                                                      \
    char* d_ = sm + (BUFOFF) + (tid << 4);                                               \
    __builtin_amdgcn_global_load_lds((GV*)(gA0 + (KO)), (LV*)d_, 16, 0, 0);              \
    __builtin_amdgcn_global_load_lds((GV*)(gA0 + 64 * (size_t)K_DIM + (KO)),             \
                                     (LV*)(d_ + 4096), 16, 0, 0);                        \
    __builtin_amdgcn_global_load_lds((GV*)(gA0 + 128 * (size_t)K_DIM + (KO)),            \
                                     (LV*)(d_ + 8192), 16, 0, 0);                        \
    __builtin_amdgcn_global_load_lds((GV*)(gA0 + 192 * (size_t)K_DIM + (KO)),            \
                                     (LV*)(d_ + 12288), 16, 0, 0);                       \
    __builtin_amdgcn_global_load_lds((GV*)(gB0 + (KO)), (LV*)(d_ + 16384), 16, 0, 0);    \
    __builtin_amdgcn_global_load_lds((GV*)(gB0 + 64 * (size_t)K_DIM + (KO)),             \
                                     (LV*)(d_ + 20480), 16, 0, 0);                       \
  }

  // ---- fragment read offsets: addr = region + row*64 + slot(kc)*16
  const int aBase = (wm * 128 + m32) * 64;          // + fm*2048
  const int bBase = 16384 + (wn * 64 + m32) * 64;   // + fn*2048
  int sl[2];
#pragma unroll
  for (int kc = 0; kc < 2; ++kc) sl[kc] = ((kc * 2 + half) ^ ((m32 >> 1) & 3)) << 4;

  i32x16 acc[4][2];
#pragma unroll
  for (int i = 0; i < 4; ++i)
#pragma unroll
    for (int j = 0; j < 2; ++j)
#pragma unroll
      for (int r = 0; r < 16; ++r) acc[i][j][r] = 0;

  // ---- prologue: stage tiles 0 and 1; gate tile 0; enter loop.
  STAGE(0, 0);
  STAGE(24576, 64);
  asm volatile("s_waitcnt vmcnt(6)" ::: "memory");  // tile 0 landed; tile 1 in flight
  __builtin_amdgcn_s_barrier();
  __builtin_amdgcn_sched_barrier(0);

  int o0 = 0, o1 = 24576, o2 = 49152;  // compute | resident-next | landing

#pragma unroll 1
  for (int t = 0; t < 64; ++t) {
    const char* bufp = sm + o0;

    // 12 ds_read_b128: every fragment of this K-tile exactly once.
    i32x4 af[2][4], bf[2][2];
#pragma unroll
    for (int kc = 0; kc < 2; ++kc) {
#pragma unroll
      for (int fm = 0; fm < 4; ++fm)
        af[kc][fm] = *(const i32x4*)(bufp + aBase + fm * 2048 + sl[kc]);
#pragma unroll
      for (int fn = 0; fn < 2; ++fn)
        bf[kc][fn] = *(const i32x4*)(bufp + bBase + fn * 2048 + sl[kc]);
    }

    if (t < 62) STAGE(o2, (size_t)(t + 2) * 64);  // tile t+2 into t-1's buffer

    __builtin_amdgcn_s_setprio(1);
#pragma unroll
    for (int kc = 0; kc < 2; ++kc)
#pragma unroll
      for (int fm = 0; fm < 4; ++fm)
#pragma unroll
        for (int fn = 0; fn < 2; ++fn)
          acc[fm][fn] =
              __builtin_amdgcn_mfma_i32_32x32x32_i8(af[kc][fm], bf[kc][fn], acc[fm][fn], 0, 0, 0);
    __builtin_amdgcn_s_setprio(0);

    if (t < 62) {
      asm volatile("s_waitcnt vmcnt(6)" ::: "memory");  // t+1 landed; t+2 in flight
    } else if (t == 62) {
      asm volatile("s_waitcnt vmcnt(0)" ::: "memory");  // tail: tile 63 landed
    }
    if (t < 63) {
      __builtin_amdgcn_s_barrier();
      __builtin_amdgcn_sched_barrier(0);
    }
    const int tmp = o0; o0 = o1; o1 = o2; o2 = tmp;
  }
#undef STAGE

  // ---- epilogue: C/D layout col=lane&31, row=(r&3)+8*(r>>2)+4*(lane>>5)
  const int col0 = bn * 128 + wn * 64 + m32;
  const float swv0 = sw[col0];
  const float swv1 = sw[col0 + 32];
  const float bv0 = bias[col0];
  const float bv1 = bias[col0 + 32];

#pragma unroll
  for (int fm = 0; fm < 4; ++fm) {
    const int rbase = bm * 256 + wm * 128 + fm * 32 + 4 * half;
    float sxv[16];
#pragma unroll
    for (int r = 0; r < 16; ++r) sxv[r] = sx[rbase + (r & 3) + 8 * (r >> 2)];
#pragma unroll
    for (int fn = 0; fn < 2; ++fn) {
      const int colg = col0 + fn * 32;
      const float swb = fn ? swv1 : swv0;
      const float bvb = fn ? bv1 : bv0;
#pragma unroll
      for (int r = 0; r < 16; ++r) {
        const int rowg = rbase + (r & 3) + 8 * (r >> 2);
        C[(size_t)rowg * N_DIM + colg] = (float)acc[fm][fn][r] * (sxv[r] * swb) + bvb;
      }
    }
  }
}

// ---------------------------------------------------------------------------
extern "C" void kernel_launch(void* const* d_in, const int* in_sizes, int n_in,
                              void* d_out, int out_size, void* d_ws, size_t ws_size,
                              hipStream_t stream) {
  const float* x = (const float*)d_in[0];     // (2,2048,4096) fp32
  const float* w = (const float*)d_in[1];     // (4096,4096) fp32 (pre-quantized)
  const float* bias = (const float*)d_in[2];  // (4096,) fp32

  char* xq = (char*)d_ws;                                   // 16 MB i8
  char* wq = xq + (size_t)M_DIM * K_DIM;                    // 16 MB i8
  float* sx = (float*)(wq + (size_t)N_DIM * K_DIM);         // 16 KB
  float* sw = sx + M_DIM;                                   // 16 KB
  float* out = (float*)d_out;

  prequant_kernel<<<2048, 256, 0, stream>>>(x, w, xq, wq, sx, sw);

  gemm_i8<<<dim3(512), dim3(256), 0, stream>>>(xq, wq, sx, sw, bias, out);
}